// Round 5
// baseline (112.162 us; speedup 1.0000x reference)
//
#include <hip/hip_runtime.h>
#include <hip/hip_bf16.h>

#define B_    8
#define Q_    64
#define C_    512
#define HW_   256
#define E_    512
#define HATT_ 128
#define HMLP_ 512
#define NCLS_ 14
#define NLAB_ 64

typedef unsigned short u16;
typedef unsigned int   u32;
typedef __attribute__((ext_vector_type(8))) short short8;   // 8 bf16
typedef __attribute__((ext_vector_type(4))) float f32x4;

// ws layout (bytes) — total 12,455,936 < 12,582,912 (proven available in R2):
//   GBp  @ 0       : 256x1024 f32 (l,cq)-partials of [gamma|beta]   1 MB
//                    ALIASED by pP (512x512 f32, 1 MB) after prep_wg read it
//   pA   @ 1048576 : 512 f32 attn mass per bq                        2 KB
//   perm @ 1050624 : 512 int  label-sorted bq list (bq | l<<16)      2 KB
//   Dlp  @ 1052672 : 256x128 f32 (l,cq)-partials of beta@W_att_h   128 KB
//   Gl   @ 1183744 : 64x512 f32 gamma per label                    128 KB
//   Bl   @ 1314816 : 64x512 f32 beta per label                     128 KB
//   W1bf @ 1445888 : 512x512 bf16 W_mlp1                           512 KB
//   fT   @ 1970176 : 8x256x512 bf16 feature^T [b][n][c]              2 MB
//   WgT  @ 4067328 : 64x128x512 bf16 gamma-scaled W_att_h^T [l][h][c] 8 MB

__device__ __forceinline__ float gelu_fast(float x) {
    // gelu via A&S 7.1.26 erf approx (|erf err| < 1.5e-7); rcp/exp on trans pipe
    const float ax = fabsf(x);
    const float t  = __builtin_amdgcn_rcpf(1.0f + 0.3275911f * ax);
    const float p  = t * (0.254829592f +
                     t * (-0.284496736f +
                     t * (1.421413741f +
                     t * (-1.453152027f +
                     t * 1.061405429f))));
    const float e  = __expf(-x * x);
    const float er = copysignf(1.0f - p * e, x);
    return 0.5f * x * (1.0f + er);
}
__device__ __forceinline__ float sigmoid_(float x) {
    return 1.0f / (1.0f + __expf(-x));
}
__device__ __forceinline__ u16 f2bf(float x) {              // RNE f32->bf16
    u32 u = __float_as_uint(x);
    u32 r = (u + 0x7fffu + ((u >> 16) & 1u)) >> 16;
    return (u16)r;
}
__device__ __forceinline__ float bf2f(u16 u) {
    return __uint_as_float(((u32)u) << 16);
}

// ---------------------------------------------------------------------------
// K1 prep_misc, 577 blocks x 256 thr:
//  [0,256)   GBp[(l,cq)][j] = sum_{c in cq-slice} qt[l][c] W_film[c][j]
//  [256,512) fT[b][n][c] = bf16(feature[b][c][n])
//  [512,576) W1bf = bf16(W_mlp1)
//  576       counting sort of label_ids -> perm (bq | l<<16, label-grouped)
// ---------------------------------------------------------------------------
__global__ __launch_bounds__(256) void prep_misc(
    const float* __restrict__ qt, const float* __restrict__ W_film,
    const float* __restrict__ feature, const float* __restrict__ W_mlp1,
    const int* __restrict__ label_ids,
    float* __restrict__ GBp, u16* __restrict__ W1bf, u16* __restrict__ fT,
    int* __restrict__ perm) {

    __shared__ __align__(16) char sm[16896];
    const int bid = blockIdx.x, t = threadIdx.x;

    if (bid < 256) {                       // ---- GB partials
        float* qrow = (float*)sm;          // 128 floats
        const int l = bid >> 2, cq = bid & 3;
        if (t < 128) qrow[t] = qt[l * E_ + cq * 128 + t];
        __syncthreads();
        const float* wp = W_film + (size_t)(cq * 128) * 1024 + t * 4;
        f32x4 a = {0.f, 0.f, 0.f, 0.f};
        #pragma unroll 8
        for (int c = 0; c < 128; ++c) {
            const float4 w = *(const float4*)(wp + (size_t)c * 1024);
            const float q = qrow[c];
            a.x += q * w.x; a.y += q * w.y; a.z += q * w.z; a.w += q * w.w;
        }
        *(f32x4*)&GBp[(size_t)bid * 1024 + t * 4] = a;
    } else if (bid < 512) {                // ---- fT transpose
        float (*tile)[65] = (float(*)[65])sm;       // 64 x 65
        const int bb = bid - 256;
        const int b = bb >> 5, c0 = ((bb >> 2) & 7) * 64, n0 = (bb & 3) * 64;
        const float* fb = feature + (size_t)b * C_ * HW_;
        const int cl = t >> 2, nq = t & 3;
        #pragma unroll
        for (int i = 0; i < 4; ++i) {
            float4 v = *(const float4*)&fb[(c0 + cl) * HW_ + n0 + nq * 16 + i * 4];
            tile[cl][nq * 16 + i * 4 + 0] = v.x;
            tile[cl][nq * 16 + i * 4 + 1] = v.y;
            tile[cl][nq * 16 + i * 4 + 2] = v.z;
            tile[cl][nq * 16 + i * 4 + 3] = v.w;
        }
        __syncthreads();
        const int nl = t >> 2, cqq = t & 3;
        u16 pk[16];
        #pragma unroll
        for (int k = 0; k < 16; ++k) pk[k] = f2bf(tile[cqq * 16 + k][nl]);
        u16* dst = fT + (size_t)(b * HW_ + n0 + nl) * C_ + c0 + cqq * 16;
        *(uint4*)dst       = *(uint4*)pk;
        *(uint4*)(dst + 8) = *(uint4*)(pk + 8);
    } else if (bid < 576) {                // ---- W1 -> bf16
        const int b2 = bid - 512;
        #pragma unroll
        for (int k = 0; k < 2; ++k) {
            const int idx = (b2 * 512 + k * 256 + t) * 8;
            float4 v0 = *(const float4*)&W_mlp1[idx];
            float4 v1 = *(const float4*)&W_mlp1[idx + 4];
            u16 pk[8] = {f2bf(v0.x), f2bf(v0.y), f2bf(v0.z), f2bf(v0.w),
                         f2bf(v1.x), f2bf(v1.y), f2bf(v1.z), f2bf(v1.w)};
            *(uint4*)&W1bf[idx] = *(uint4*)pk;
        }
    } else {                               // ---- counting sort by label
        int* cnt = (int*)sm;               // 64
        if (t < 64) cnt[t] = 0;
        __syncthreads();
        const int l0 = label_ids[t], l1 = label_ids[t + 256];
        atomicAdd(&cnt[l0], 1);
        atomicAdd(&cnt[l1], 1);
        __syncthreads();
        if (t == 0) {
            int run = 0;
            for (int i = 0; i < 64; ++i) { const int c = cnt[i]; cnt[i] = run; run += c; }
        }
        __syncthreads();
        const int p0 = atomicAdd(&cnt[l0], 1);
        perm[p0] = t | (l0 << 16);
        const int p1 = atomicAdd(&cnt[l1], 1);
        perm[p1] = (t + 256) | (l1 << 16);
    }
}

// ---------------------------------------------------------------------------
// K2 prep_wg: 256 blocks (l, cq) x 256 thr.
//   Gl/Bl[l][c] = b_film + sum GBp partials   (c in cq-slice)
//   WgT[l][h][c] = bf16(gamma_l[c] * W_att_h[c][h])
//   Dlp[(l,cq)][h] = sum_{c slice} beta_l[c] * W_att_h[c][h]
// ---------------------------------------------------------------------------
__global__ __launch_bounds__(256) void prep_wg(
    const float* __restrict__ b_film, const float* __restrict__ W_att_h,
    const float* __restrict__ GBp,
    float* __restrict__ Gl, float* __restrict__ Bl,
    u16* __restrict__ WgT, float* __restrict__ Dlp) {

    __shared__ float g_s[128], b_s[128], dred[256];
    const int bid = blockIdx.x, t = threadIdx.x;
    const int l = bid >> 2, cq = bid & 3;

    if (t < 128) {
        const int c = cq * 128 + t;
        float g = b_film[c], be = b_film[512 + c];
        #pragma unroll
        for (int j = 0; j < 4; ++j) {
            g  += GBp[(size_t)(l * 4 + j) * 1024 + c];
            be += GBp[(size_t)(l * 4 + j) * 1024 + 512 + c];
        }
        g_s[t] = g; b_s[t] = be;
        Gl[l * C_ + c] = g;
        Bl[l * C_ + c] = be;
    }
    __syncthreads();

    const int h = t & 127, ch = t >> 7;
    float dl = 0.f;
    u16* dst = WgT + (size_t)l * (HATT_ * C_) + (size_t)h * C_ + cq * 128 + ch * 64;
    #pragma unroll
    for (int grp = 0; grp < 8; ++grp) {
        u16 pk[8];
        #pragma unroll
        for (int i = 0; i < 8; ++i) {
            const int cl = ch * 64 + grp * 8 + i;
            const float w = W_att_h[(size_t)(cq * 128 + cl) * HATT_ + h];
            pk[i] = f2bf(g_s[cl] * w);
            dl += b_s[cl] * w;
        }
        *(uint4*)(dst + grp * 8) = *(uint4*)pk;
    }
    dred[ch * 128 + h] = dl;
    __syncthreads();
    if (t < 128)
        Dlp[(size_t)(l * 4 + cq) * 128 + t] = dred[t] + dred[128 + t];
}

// ---------------------------------------------------------------------------
// K3 attn_gemm: 512 blocks x 512 thr (8 waves, 4 wm x 2 wc), one bq each,
// label-sorted so each XCD (idx&7) gets a contiguous label chunk (~1 MB WgT).
// Barrier-free K-loop: A (fT) and B (WgT, pre-scaled) fragments streamed
// straight from L1/L2. Epilogue: gelu -> attn -> p[c] partial pool -> ws.
// ---------------------------------------------------------------------------
__global__ __launch_bounds__(512, 4) void attn_gemm(
    const float* __restrict__ W_att_f, const float* __restrict__ b_att_f,
    const float* __restrict__ b_att_h, const float* __restrict__ Dlp,
    const int*   __restrict__ perm,    const u16* __restrict__ WgT,
    const u16*   __restrict__ fT,
    float* __restrict__ pP, float* __restrict__ pA) {

    __shared__ float attn_part[2][HW_];
    __shared__ float attn_s[HW_];
    __shared__ float d_s[HATT_];
    __shared__ float wf_s[HATT_];

    const int t = threadIdx.x;
    const int idx = blockIdx.x;
    const int srank = (idx & 7) * 64 + (idx >> 3);   // XCD-chunked sorted rank
    const int pe = perm[srank];
    const int bq = pe & 0xffff, l = pe >> 16;
    const int b = bq >> 6;

    if (t < HATT_) {
        d_s[t] = b_att_h[t]
               + Dlp[(size_t)(l * 4 + 0) * 128 + t]
               + Dlp[(size_t)(l * 4 + 1) * 128 + t]
               + Dlp[(size_t)(l * 4 + 2) * 128 + t]
               + Dlp[(size_t)(l * 4 + 3) * 128 + t];
        wf_s[t] = W_att_f[t];
    }

    const int lane = t & 63, w = t >> 6;
    const int wm = w >> 1, wc = w & 1;          // 4 n-quarters x 2 h-halves
    const int lr = lane & 15, lk = lane >> 4;
    const u16* Ab = fT + (size_t)b * HW_ * C_ + (size_t)(wm * 64 + lr) * C_ + lk * 8;
    const u16* Bb = WgT + (size_t)l * (HATT_ * C_) + (size_t)(wc * 64 + lr) * C_ + lk * 8;

    const f32x4 zero = {0.f, 0.f, 0.f, 0.f};
    f32x4 acc[4][4];
    #pragma unroll
    for (int mi = 0; mi < 4; ++mi)
        #pragma unroll
        for (int ni = 0; ni < 4; ++ni) acc[mi][ni] = zero;

    #pragma unroll 2
    for (int s = 0; s < 16; ++s) {
        const int ck = s * 32;
        short8 af[4], bf[4];
        #pragma unroll
        for (int mi = 0; mi < 4; ++mi)
            af[mi] = *(const short8*)(Ab + (size_t)mi * 16 * C_ + ck);
        #pragma unroll
        for (int ni = 0; ni < 4; ++ni)
            bf[ni] = *(const short8*)(Bb + (size_t)ni * 16 * C_ + ck);
        #pragma unroll
        for (int mi = 0; mi < 4; ++mi)
            #pragma unroll
            for (int ni = 0; ni < 4; ++ni)
                acc[mi][ni] = __builtin_amdgcn_mfma_f32_16x16x32_bf16(
                    af[mi], bf[ni], acc[mi][ni], 0, 0, 0);
    }
    __syncthreads();   // d_s/wf_s ready; K-loop done

    // epilogue: gelu(hidden + D) . wf  (C/D: col(h)=lr, row(n)=lk*4+j)
    #pragma unroll
    for (int mi = 0; mi < 4; ++mi) {
        #pragma unroll
        for (int j = 0; j < 4; ++j) {
            float sum = 0.f;
            #pragma unroll
            for (int ni = 0; ni < 4; ++ni) {
                const int h = wc * 64 + ni * 16 + lr;
                sum += gelu_fast(acc[mi][ni][j] + d_s[h]) * wf_s[h];
            }
            sum += __shfl_xor(sum, 1);
            sum += __shfl_xor(sum, 2);
            sum += __shfl_xor(sum, 4);
            sum += __shfl_xor(sum, 8);
            if (lr == 0) attn_part[wc][wm * 64 + mi * 16 + lk * 4 + j] = sum;
        }
    }
    __syncthreads();
    if (t < HW_)
        attn_s[t] = sigmoid_(attn_part[0][t] + attn_part[1][t] + b_att_f[0]);
    __syncthreads();
    if (t < 64) {
        float a = attn_s[t] + attn_s[t + 64] + attn_s[t + 128] + attn_s[t + 192];
        #pragma unroll
        for (int m = 1; m < 64; m <<= 1) a += __shfl_xor(a, m);
        if (t == 0) pA[bq] = a;
    }

    // p[c] = sum_n attn[n] * fT[n][c]; thread t owns c = t
    {
        const u16* fc = fT + (size_t)b * HW_ * C_ + t;
        float p = 0.f;
        #pragma unroll 8
        for (int n = 0; n < HW_; ++n) p += attn_s[n] * bf2f(fc[(size_t)n * C_]);
        pP[(size_t)bq * C_ + t] = p;
    }
}

// ---------------------------------------------------------------------------
// K4 mlp_head: 256 blocks x 512 thr, 2 bq per block.
// pooled = (Gl*p + Bl*A)/(A+eps); z = gelu(pooled@W1+b1); out = z@W2 + b2.
// ---------------------------------------------------------------------------
__global__ __launch_bounds__(512) void mlp_head(
    const int*   __restrict__ label_ids,
    const float* __restrict__ Gl, const float* __restrict__ Bl,
    const float* __restrict__ b_mlp1, const float* __restrict__ W_mlp2,
    const float* __restrict__ b_mlp2, const float* __restrict__ pP,
    const float* __restrict__ pA,     const u16* __restrict__ W1bf,
    float* __restrict__ out) {

    __shared__ float pooled_s[2][C_];
    __shared__ float zred[2][2][HMLP_];
    __shared__ float z_s[2][HMLP_];
    __shared__ float red_s[32 * NCLS_];

    const int t = threadIdx.x;
    const int bq0 = blockIdx.x * 2;

    {   // pooled for both bq (each thread: one bqi, two c)
        const int bqi = t >> 8, cc = (t & 255) * 2;
        const int bq = bq0 + bqi, l = label_ids[bq];
        const float A = pA[bq];
        const float inv = 1.0f / (A + 1e-8f);
        #pragma unroll
        for (int i = 0; i < 2; ++i) {
            const int c = cc + i;
            const float p = pP[(size_t)bq * C_ + c];
            pooled_s[bqi][c] = (Gl[l * C_ + c] * p + Bl[l * C_ + c] * A) * inv;
        }
    }
    __syncthreads();

    {   // z = pooled @ W1 (c-split x2, h-pair per thread, both bq)
        const int hp = t & 255, cg = t >> 8;
        float z00 = 0.f, z01 = 0.f, z10 = 0.f, z11 = 0.f;
        const u16* wp = W1bf + hp * 2;
        #pragma unroll 8
        for (int c = cg * 256; c < cg * 256 + 256; ++c) {
            const u32 v = *(const u32*)(wp + (size_t)c * HMLP_);
            const float w0 = __uint_as_float(v << 16);
            const float w1 = __uint_as_float(v & 0xffff0000u);
            const float pa = pooled_s[0][c], pb = pooled_s[1][c];
            z00 += pa * w0; z01 += pa * w1;
            z10 += pb * w0; z11 += pb * w1;
        }
        float2 a0 = {z00, z01}, a1 = {z10, z11};
        *(float2*)&zred[cg][0][hp * 2] = a0;
        *(float2*)&zred[cg][1][hp * 2] = a1;
    }
    __syncthreads();
    {
        const int bqi = t >> 8, h2 = (t & 255) * 2;
        #pragma unroll
        for (int i = 0; i < 2; ++i) {
            const int h = h2 + i;
            z_s[bqi][h] = gelu_fast(zred[0][bqi][h] + zred[1][bqi][h] + b_mlp1[h]);
        }
    }
    __syncthreads();

    #pragma unroll
    for (int bqi = 0; bqi < 2; ++bqi) {
        if (t < 448) {
            const int o = t % 14, seg = t / 14;
            float s = 0.f;
            #pragma unroll
            for (int k = 0; k < 16; ++k) {
                const int h = seg * 16 + k;
                s += z_s[bqi][h] * W_mlp2[h * NCLS_ + o];
            }
            red_s[seg * NCLS_ + o] = s;
        }
        __syncthreads();
        if (t < NCLS_) {
            float s = b_mlp2[t];
            #pragma unroll
            for (int seg = 0; seg < 32; ++seg) s += red_s[seg * NCLS_ + t];
            out[(bq0 + bqi) * NCLS_ + t] = s;
        }
        __syncthreads();
    }
}

// ---------------------------------------------------------------------------
extern "C" void kernel_launch(void* const* d_in, const int* in_sizes, int n_in,
                              void* d_out, int out_size, void* d_ws, size_t ws_size,
                              hipStream_t stream) {
    const float* feature   = (const float*)d_in[0];
    const int*   label_ids = (const int*)  d_in[1];
    const float* qt        = (const float*)d_in[2];
    const float* W_film    = (const float*)d_in[3];
    const float* b_film    = (const float*)d_in[4];
    const float* W_att_h   = (const float*)d_in[5];
    const float* b_att_h   = (const float*)d_in[6];
    const float* W_att_f   = (const float*)d_in[7];
    const float* b_att_f   = (const float*)d_in[8];
    const float* W_mlp1    = (const float*)d_in[9];
    const float* b_mlp1    = (const float*)d_in[10];
    const float* W_mlp2    = (const float*)d_in[11];
    const float* b_mlp2    = (const float*)d_in[12];
    float* out = (float*)d_out;

    char* wsb   = (char*)d_ws;
    float* GBp  = (float*)wsb;                   // 1 MB   (k1 -> k2)
    float* pP   = (float*)wsb;                   // 1 MB   (k3 -> k4, aliases GBp)
    float* pA   = (float*)(wsb + 1048576);       // 2 KB
    int*   perm = (int*)  (wsb + 1050624);       // 2 KB
    float* Dlp  = (float*)(wsb + 1052672);       // 128 KB
    float* Gl   = (float*)(wsb + 1183744);       // 128 KB
    float* Bl   = (float*)(wsb + 1314816);       // 128 KB
    u16*   W1bf = (u16*)  (wsb + 1445888);       // 512 KB
    u16*   fTp  = (u16*)  (wsb + 1970176);       // 2 MB
    u16*   WgT  = (u16*)  (wsb + 4067328);       // 8 MB

    hipLaunchKernelGGL(prep_misc, dim3(577), dim3(256), 0, stream,
                       qt, W_film, feature, W_mlp1, label_ids,
                       GBp, W1bf, fTp, perm);
    hipLaunchKernelGGL(prep_wg, dim3(256), dim3(256), 0, stream,
                       b_film, W_att_h, GBp, Gl, Bl, WgT, Dlp);
    hipLaunchKernelGGL(attn_gemm, dim3(512), dim3(512), 0, stream,
                       W_att_f, b_att_f, b_att_h, Dlp, perm, WgT, fTp, pP, pA);
    hipLaunchKernelGGL(mlp_head, dim3(256), dim3(512), 0, stream,
                       label_ids, Gl, Bl, b_mlp1, W_mlp2, b_mlp2,
                       pP, pA, W1bf, out);
}

// Round 6
// 87.900 us; speedup vs baseline: 1.2760x; 1.2760x over previous
//
#include <hip/hip_runtime.h>
#include <hip/hip_bf16.h>

#define B_    8
#define Q_    64
#define C_    512
#define HW_   256
#define E_    512
#define HATT_ 128
#define HMLP_ 512
#define NCLS_ 14
#define NLAB_ 64

typedef unsigned short u16;
typedef unsigned int   u32;
typedef __attribute__((ext_vector_type(8))) short short8;   // 8 bf16
typedef __attribute__((ext_vector_type(4))) float f32x4;

// ws layout (bytes):
//   GBp  @ 0       : 256x1024 f32 (l,cq)-partials of [gamma|beta]   1 MB
//   pA   @ 1048576 : 512 f32                                         2 KB
//   WT   @ 1052672 : 128x512 bf16 W_att_h^T [h][c]                 128 KB
//   W1bf @ 1183744 : 512x512 bf16 W_mlp1                           512 KB
//   fT   @ 1708032 : 8x256x512 bf16 feature^T [b][n][c]              2 MB
//   pP   @ 3805184 : 512x512 f32 attn-weighted pooled partials       1 MB
// total ~4.8 MB

__device__ __forceinline__ float gelu_fast(float x) {
    // gelu via A&S 7.1.26 erf approx (|erf err| < 1.5e-7); rcp/exp on trans pipe
    const float ax = fabsf(x);
    const float t  = __builtin_amdgcn_rcpf(1.0f + 0.3275911f * ax);
    const float p  = t * (0.254829592f +
                     t * (-0.284496736f +
                     t * (1.421413741f +
                     t * (-1.453152027f +
                     t * 1.061405429f))));
    const float e  = __expf(-x * x);
    const float er = copysignf(1.0f - p * e, x);
    return 0.5f * x * (1.0f + er);
}
__device__ __forceinline__ float sigmoid_(float x) {
    return 1.0f / (1.0f + __expf(-x));
}
__device__ __forceinline__ u16 f2bf(float x) {              // RNE f32->bf16
    u32 u = __float_as_uint(x);
    u32 r = (u + 0x7fffu + ((u >> 16) & 1u)) >> 16;
    return (u16)r;
}
__device__ __forceinline__ float bf2f(u16 u) {
    return __uint_as_float(((u32)u) << 16);
}
__device__ __forceinline__ u32 cvt_pk_bf16(float lo, float hi) {
    u32 r;
    asm("v_cvt_pk_bf16_f32 %0, %1, %2" : "=v"(r) : "v"(lo), "v"(hi));
    return r;
}

// ---------------------------------------------------------------------------
// K1 prep_misc, 592 blocks x 256 thr:
//  [0,256)   GBp[(l,cq)][j] = sum_{c in cq-slice} qt[l][c] W_film[c][j]
//  [256,272) WT[h][c] = bf16(W_att_h[c][h])
//  [272,528) fT[b][n][c] = bf16(feature[b][c][n])
//  [528,592) W1bf = bf16(W_mlp1)
// ---------------------------------------------------------------------------
__global__ __launch_bounds__(256) void prep_misc(
    const float* __restrict__ qt, const float* __restrict__ W_film,
    const float* __restrict__ W_att_h, const float* __restrict__ feature,
    const float* __restrict__ W_mlp1,
    float* __restrict__ GBp, u16* __restrict__ WT,
    u16* __restrict__ W1bf, u16* __restrict__ fT) {

    __shared__ __align__(16) char sm[16896];
    const int bid = blockIdx.x, t = threadIdx.x;

    if (bid < 256) {                       // ---- GB partials
        float* qrow = (float*)sm;          // 128 floats
        const int l = bid >> 2, cq = bid & 3;
        if (t < 128) qrow[t] = qt[l * E_ + cq * 128 + t];
        __syncthreads();
        const float* wp = W_film + (size_t)(cq * 128) * 1024 + t * 4;
        f32x4 a = {0.f, 0.f, 0.f, 0.f};
        #pragma unroll 8
        for (int c = 0; c < 128; ++c) {
            const float4 w = *(const float4*)(wp + (size_t)c * 1024);
            const float q = qrow[c];
            a.x += q * w.x; a.y += q * w.y; a.z += q * w.z; a.w += q * w.w;
        }
        *(f32x4*)&GBp[(size_t)bid * 1024 + t * 4] = a;
    } else if (bid < 272) {                // ---- WT transpose (bf16)
        float (*tile)[129] = (float(*)[129])sm;     // 32 x 129
        const int c0 = (bid - 256) * 32;
        const int cl = t >> 3, hq = t & 7;
        #pragma unroll
        for (int i = 0; i < 4; ++i) {
            const int h = hq * 16 + i * 4;
            *(float4*)&tile[cl][h] = *(const float4*)&W_att_h[(c0 + cl) * HATT_ + h];
        }
        __syncthreads();
        const int h = t >> 1, half_ = t & 1;
        u16 pk[16];
        #pragma unroll
        for (int i = 0; i < 16; ++i) pk[i] = f2bf(tile[half_ * 16 + i][h]);
        u16* dst = WT + (size_t)h * C_ + c0 + half_ * 16;
        *(uint4*)dst       = *(uint4*)pk;
        *(uint4*)(dst + 8) = *(uint4*)(pk + 8);
    } else if (bid < 528) {                // ---- fT transpose
        float (*tile)[65] = (float(*)[65])sm;       // 64 x 65
        const int bb = bid - 272;
        const int b = bb >> 5, c0 = ((bb >> 2) & 7) * 64, n0 = (bb & 3) * 64;
        const float* fb = feature + (size_t)b * C_ * HW_;
        const int cl = t >> 2, nq = t & 3;
        #pragma unroll
        for (int i = 0; i < 4; ++i) {
            float4 v = *(const float4*)&fb[(c0 + cl) * HW_ + n0 + nq * 16 + i * 4];
            tile[cl][nq * 16 + i * 4 + 0] = v.x;
            tile[cl][nq * 16 + i * 4 + 1] = v.y;
            tile[cl][nq * 16 + i * 4 + 2] = v.z;
            tile[cl][nq * 16 + i * 4 + 3] = v.w;
        }
        __syncthreads();
        const int nl = t >> 2, cqq = t & 3;
        u16 pk[16];
        #pragma unroll
        for (int k = 0; k < 16; ++k) pk[k] = f2bf(tile[cqq * 16 + k][nl]);
        u16* dst = fT + (size_t)(b * HW_ + n0 + nl) * C_ + c0 + cqq * 16;
        *(uint4*)dst       = *(uint4*)pk;
        *(uint4*)(dst + 8) = *(uint4*)(pk + 8);
    } else {                               // ---- W1 -> bf16
        const int b2 = bid - 528;
        #pragma unroll
        for (int k = 0; k < 2; ++k) {
            const int idx = (b2 * 512 + k * 256 + t) * 8;
            float4 v0 = *(const float4*)&W_mlp1[idx];
            float4 v1 = *(const float4*)&W_mlp1[idx + 4];
            u16 pk[8] = {f2bf(v0.x), f2bf(v0.y), f2bf(v0.z), f2bf(v0.w),
                         f2bf(v1.x), f2bf(v1.y), f2bf(v1.z), f2bf(v1.w)};
            *(uint4*)&W1bf[idx] = *(uint4*)pk;
        }
    }
}

// ---------------------------------------------------------------------------
// K2 attn_gemm: 512 blocks x 512 thr (8 waves: 4 wm x 2 wc), one bq each.
// b = blockIdx&7 pins each batch row to one XCD (fT[b] 256KB L2-resident).
// Prologue (2 barriers total): gamma/beta from GBp; stage FULL gamma-scaled
// B (128h x 512c bf16 = 128KB) into XOR-swizzled LDS, fusing the d = beta.W
// dot into the same pass. Then a BARRIER-FREE K-loop: A streamed from L2
// with 2-deep register prefetch, B via swizzled ds_read_b128, 256 MFMAs.
// Epilogue: gelu -> attn -> A-mass + pooled partials to ws.
// ---------------------------------------------------------------------------
__global__ __launch_bounds__(512) void attn_gemm(
    const int*   __restrict__ label_ids,
    const float* __restrict__ W_att_f, const float* __restrict__ b_att_f,
    const float* __restrict__ b_film,  const float* __restrict__ b_att_h,
    const float* __restrict__ GBp,     const u16* __restrict__ WT,
    const u16*   __restrict__ fT,
    float* __restrict__ pP, float* __restrict__ pA) {

    __shared__ __align__(16) char Bsh[131072];     // 128h x 512c bf16, swizzled
    __shared__ float gamma_s[C_];
    __shared__ float beta_s[C_];
    __shared__ float dred[512];
    __shared__ float d_s[HATT_];
    __shared__ float wf_s[HATT_];
    __shared__ float attn_part[2][HW_];
    __shared__ float attn_s[HW_];

    const int t = threadIdx.x;
    const int idx = blockIdx.x;
    const int b = idx & 7, q = idx >> 3;
    const int bq = b * 64 + q, l = label_ids[bq];

    // ---- gamma/beta (inline GBp reduce), wf
    {
        float g = b_film[t], be = b_film[512 + t];
        #pragma unroll
        for (int j = 0; j < 4; ++j) {
            g  += GBp[(size_t)(l * 4 + j) * 1024 + t];
            be += GBp[(size_t)(l * 4 + j) * 1024 + 512 + t];
        }
        gamma_s[t] = g; beta_s[t] = be;
        if (t < HATT_) wf_s[t] = W_att_f[t];
    }
    __syncthreads();

    // ---- stage B once: row h = t>>2, c-part = t&3 (16 uint4 per thread);
    //      fused d-partial = sum beta[c]*W[c][h]
    {
        const int sh = t >> 2, scp = t & 3;
        const u16* wrow = WT + (size_t)sh * C_;
        char* brow = Bsh + sh * 1024;
        const int swz = (sh & 7) << 4;
        float dp = 0.f;
        #pragma unroll
        for (int i = 0; i < 16; ++i) {
            const int c = i * 32 + scp * 8;
            const uint4 wv = *(const uint4*)(wrow + c);
            const float w0 = bf2f((u16)(wv.x & 0xffff)), w1 = bf2f((u16)(wv.x >> 16));
            const float w2 = bf2f((u16)(wv.y & 0xffff)), w3 = bf2f((u16)(wv.y >> 16));
            const float w4 = bf2f((u16)(wv.z & 0xffff)), w5 = bf2f((u16)(wv.z >> 16));
            const float w6 = bf2f((u16)(wv.w & 0xffff)), w7 = bf2f((u16)(wv.w >> 16));
            const float4 g0 = *(const float4*)&gamma_s[c];
            const float4 g1 = *(const float4*)&gamma_s[c + 4];
            const float4 e0 = *(const float4*)&beta_s[c];
            const float4 e1 = *(const float4*)&beta_s[c + 4];
            dp += e0.x * w0 + e0.y * w1 + e0.z * w2 + e0.w * w3
                + e1.x * w4 + e1.y * w5 + e1.z * w6 + e1.w * w7;
            uint4 rr;
            rr.x = cvt_pk_bf16(w0 * g0.x, w1 * g0.y);
            rr.y = cvt_pk_bf16(w2 * g0.z, w3 * g0.w);
            rr.z = cvt_pk_bf16(w4 * g1.x, w5 * g1.y);
            rr.w = cvt_pk_bf16(w6 * g1.z, w7 * g1.w);
            *(uint4*)(brow + ((c * 2) ^ swz)) = rr;
        }
        dred[t] = dp;
    }
    __syncthreads();                                   // Bsh + dred ready

    // ---- barrier-free K-loop --------------------------------------------
    const int lane = t & 63, w = t >> 6;
    const int wm = w >> 1, wc = w & 1;                 // 4 n-quarters x 2 h-halves
    const int lr = lane & 15, lk = lane >> 4;
    const u16* Ab = fT + (size_t)b * HW_ * C_
                       + (size_t)(wm * 64 + lr) * C_ + lk * 8;

    const f32x4 zero = {0.f, 0.f, 0.f, 0.f};
    f32x4 acc[4][4];
    #pragma unroll
    for (int mi = 0; mi < 4; ++mi)
        #pragma unroll
        for (int ni = 0; ni < 4; ++ni) acc[mi][ni] = zero;

    short8 afA[4], afB[4], bf[4];
    #pragma unroll
    for (int mi = 0; mi < 4; ++mi)
        afA[mi] = *(const short8*)(Ab + (size_t)mi * 16 * C_);

    #pragma unroll
    for (int s = 0; s < 16; ++s) {
        const int ck2 = s * 64 + lk * 16;              // byte offset of k-chunk
        // prefetch next A into the other register bank
        if (s + 1 < 16) {
            if ((s & 1) == 0) {
                #pragma unroll
                for (int mi = 0; mi < 4; ++mi)
                    afB[mi] = *(const short8*)(Ab + (size_t)mi * 16 * C_ + (s + 1) * 32);
            } else {
                #pragma unroll
                for (int mi = 0; mi < 4; ++mi)
                    afA[mi] = *(const short8*)(Ab + (size_t)mi * 16 * C_ + (s + 1) * 32);
            }
        }
        #pragma unroll
        for (int ni = 0; ni < 4; ++ni) {
            const int h = wc * 64 + ni * 16 + lr;
            bf[ni] = *(const short8*)(Bsh + h * 1024 + (ck2 ^ ((h & 7) << 4)));
        }
        #pragma unroll
        for (int mi = 0; mi < 4; ++mi) {
            const short8 a = (s & 1) ? afB[mi] : afA[mi];
            #pragma unroll
            for (int ni = 0; ni < 4; ++ni)
                acc[mi][ni] = __builtin_amdgcn_mfma_f32_16x16x32_bf16(
                    a, bf[ni], acc[mi][ni], 0, 0, 0);
        }
    }

    // ---- d reduce (dred persists; Bsh untouched since staging)
    if (t < HATT_)
        d_s[t] = b_att_h[t] + dred[t * 4] + dred[t * 4 + 1]
                            + dred[t * 4 + 2] + dred[t * 4 + 3];
    __syncthreads();

    // ---- epilogue: gelu(hidden + D) . wf  (C/D: col(h)=lr, row(n)=lk*4+j)
    #pragma unroll
    for (int mi = 0; mi < 4; ++mi) {
        #pragma unroll
        for (int j = 0; j < 4; ++j) {
            float sum = 0.f;
            #pragma unroll
            for (int ni = 0; ni < 4; ++ni) {
                const int h = wc * 64 + ni * 16 + lr;
                sum += gelu_fast(acc[mi][ni][j] + d_s[h]) * wf_s[h];
            }
            sum += __shfl_xor(sum, 1);
            sum += __shfl_xor(sum, 2);
            sum += __shfl_xor(sum, 4);
            sum += __shfl_xor(sum, 8);
            if (lr == 0) attn_part[wc][wm * 64 + mi * 16 + lk * 4 + j] = sum;
        }
    }
    __syncthreads();
    if (t < HW_)
        attn_s[t] = sigmoid_(attn_part[0][t] + attn_part[1][t] + b_att_f[0]);
    __syncthreads();
    if (t < 64) {
        float a = attn_s[t] + attn_s[t + 64] + attn_s[t + 128] + attn_s[t + 192];
        #pragma unroll
        for (int m = 1; m < 64; m <<= 1) a += __shfl_xor(a, m);
        if (t == 0) pA[bq] = a;
    }

    // ---- p[c] = sum_n attn[n] * fT[n][c]; thread t owns c = t
    {
        const u16* fc = fT + (size_t)b * HW_ * C_ + t;
        float p0 = 0.f, p1 = 0.f, p2 = 0.f, p3 = 0.f;
        #pragma unroll 4
        for (int n = 0; n < HW_; n += 4) {
            p0 += attn_s[n]     * bf2f(fc[(size_t)n * C_]);
            p1 += attn_s[n + 1] * bf2f(fc[(size_t)(n + 1) * C_]);
            p2 += attn_s[n + 2] * bf2f(fc[(size_t)(n + 2) * C_]);
            p3 += attn_s[n + 3] * bf2f(fc[(size_t)(n + 3) * C_]);
        }
        pP[(size_t)bq * C_ + t] = (p0 + p1) + (p2 + p3);
    }
}

// ---------------------------------------------------------------------------
// K3 mlp_head: 256 blocks x 512 thr, 2 bq per block.
// pooled = (gamma*p + beta*A)/(A+eps); z = gelu(pooled@W1+b1); out = z@W2+b2.
// ---------------------------------------------------------------------------
__global__ __launch_bounds__(512) void mlp_head(
    const int*   __restrict__ label_ids,
    const float* __restrict__ b_film, const float* __restrict__ GBp,
    const float* __restrict__ b_mlp1, const float* __restrict__ W_mlp2,
    const float* __restrict__ b_mlp2, const float* __restrict__ pP,
    const float* __restrict__ pA,     const u16* __restrict__ W1bf,
    float* __restrict__ out) {

    __shared__ float pooled_s[2][C_];
    __shared__ float zred[2][2][HMLP_];
    __shared__ float z_s[2][HMLP_];
    __shared__ float red_s[32 * NCLS_];

    const int t = threadIdx.x;
    const int bq0 = blockIdx.x * 2;

    {   // pooled for both bq (each thread: one bqi, two c)
        const int bqi = t >> 8, cc = (t & 255) * 2;
        const int bq = bq0 + bqi, l = label_ids[bq];
        const float A = pA[bq];
        const float inv = 1.0f / (A + 1e-8f);
        #pragma unroll
        for (int i = 0; i < 2; ++i) {
            const int c = cc + i;
            const float p = pP[(size_t)bq * C_ + c];
            float g = b_film[c], be = b_film[512 + c];
            #pragma unroll
            for (int j = 0; j < 4; ++j) {
                g  += GBp[(size_t)(l * 4 + j) * 1024 + c];
                be += GBp[(size_t)(l * 4 + j) * 1024 + 512 + c];
            }
            pooled_s[bqi][c] = (g * p + be * A) * inv;
        }
    }
    __syncthreads();

    {   // z = pooled @ W1 (c-split x2, h-pair per thread, both bq)
        const int hp = t & 255, cg = t >> 8;
        float z00 = 0.f, z01 = 0.f, z10 = 0.f, z11 = 0.f;
        const u16* wp = W1bf + hp * 2;
        #pragma unroll 8
        for (int c = cg * 256; c < cg * 256 + 256; ++c) {
            const u32 v = *(const u32*)(wp + (size_t)c * HMLP_);
            const float w0 = __uint_as_float(v << 16);
            const float w1 = __uint_as_float(v & 0xffff0000u);
            const float pa = pooled_s[0][c], pb = pooled_s[1][c];
            z00 += pa * w0; z01 += pa * w1;
            z10 += pb * w0; z11 += pb * w1;
        }
        float2 a0 = {z00, z01}, a1 = {z10, z11};
        *(float2*)&zred[cg][0][hp * 2] = a0;
        *(float2*)&zred[cg][1][hp * 2] = a1;
    }
    __syncthreads();
    {
        const int bqi = t >> 8, h2 = (t & 255) * 2;
        #pragma unroll
        for (int i = 0; i < 2; ++i) {
            const int h = h2 + i;
            z_s[bqi][h] = gelu_fast(zred[0][bqi][h] + zred[1][bqi][h] + b_mlp1[h]);
        }
    }
    __syncthreads();

    #pragma unroll
    for (int bqi = 0; bqi < 2; ++bqi) {
        if (t < 448) {
            const int o = t % 14, seg = t / 14;
            float s = 0.f;
            #pragma unroll
            for (int k = 0; k < 16; ++k) {
                const int h = seg * 16 + k;
                s += z_s[bqi][h] * W_mlp2[h * NCLS_ + o];
            }
            red_s[seg * NCLS_ + o] = s;
        }
        __syncthreads();
        if (t < NCLS_) {
            float s = b_mlp2[t];
            #pragma unroll
            for (int seg = 0; seg < 32; ++seg) s += red_s[seg * NCLS_ + t];
            out[(bq0 + bqi) * NCLS_ + t] = s;
        }
        __syncthreads();
    }
}

// ---------------------------------------------------------------------------
extern "C" void kernel_launch(void* const* d_in, const int* in_sizes, int n_in,
                              void* d_out, int out_size, void* d_ws, size_t ws_size,
                              hipStream_t stream) {
    const float* feature   = (const float*)d_in[0];
    const int*   label_ids = (const int*)  d_in[1];
    const float* qt        = (const float*)d_in[2];
    const float* W_film    = (const float*)d_in[3];
    const float* b_film    = (const float*)d_in[4];
    const float* W_att_h   = (const float*)d_in[5];
    const float* b_att_h   = (const float*)d_in[6];
    const float* W_att_f   = (const float*)d_in[7];
    const float* b_att_f   = (const float*)d_in[8];
    const float* W_mlp1    = (const float*)d_in[9];
    const float* b_mlp1    = (const float*)d_in[10];
    const float* W_mlp2    = (const float*)d_in[11];
    const float* b_mlp2    = (const float*)d_in[12];
    float* out = (float*)d_out;

    char* wsb   = (char*)d_ws;
    float* GBp  = (float*)wsb;                   // 1 MB
    float* pA   = (float*)(wsb + 1048576);       // 2 KB
    u16*   WT   = (u16*)  (wsb + 1052672);       // 128 KB
    u16*   W1bf = (u16*)  (wsb + 1183744);       // 512 KB
    u16*   fTp  = (u16*)  (wsb + 1708032);       // 2 MB
    float* pP   = (float*)(wsb + 3805184);       // 1 MB

    hipLaunchKernelGGL(prep_misc, dim3(592), dim3(256), 0, stream,
                       qt, W_film, W_att_h, feature, W_mlp1,
                       GBp, WT, W1bf, fTp);
    hipLaunchKernelGGL(attn_gemm, dim3(512), dim3(512), 0, stream,
                       label_ids, W_att_f, b_att_f, b_film, b_att_h,
                       GBp, WT, fTp, pP, pA);
    hipLaunchKernelGGL(mlp_head, dim3(256), dim3(512), 0, stream,
                       label_ids, b_film, GBp, b_mlp1, W_mlp2, b_mlp2,
                       pP, pA, W1bf, out);
}

// Round 7
// 86.808 us; speedup vs baseline: 1.2921x; 1.0126x over previous
//
#include <hip/hip_runtime.h>
#include <hip/hip_bf16.h>

#define B_    8
#define Q_    64
#define C_    512
#define HW_   256
#define E_    512
#define HATT_ 128
#define HMLP_ 512
#define NCLS_ 14
#define NLAB_ 64

typedef unsigned short u16;
typedef unsigned int   u32;
typedef __attribute__((ext_vector_type(8))) short short8;   // 8 bf16
typedef __attribute__((ext_vector_type(4))) float f32x4;

// ws layout (bytes) — total 12,455,936 < 12,582,912 (proven available R2):
//   GBp  @ 0       : 256x1024 f32 (l,cq)-partials of [gamma|beta]   1 MB
//                    (aliased by pP 512x512 f32 after prep_wg consumed it)
//   pA   @ 1048576 : 512 f32 attn mass per bq                        2 KB
//   perm @ 1050624 : 512 int label-sorted bq list (bq | l<<16)       2 KB
//   Dlp  @ 1052672 : 256x128 f32 (l,cq)-partials of beta@W_att_h   128 KB
//   Gl   @ 1183744 : 64x512 f32 gamma per label                    128 KB
//   Bl   @ 1314816 : 64x512 f32 beta per label                     128 KB
//   W1bf @ 1445888 : 512x512 bf16 W_mlp1                           512 KB
//   fT   @ 1970176 : 8x256x512 bf16 feature^T [b][n][c]              2 MB
//   WgT  @ 4067328 : 64 x [8ss][128h][8slot] bf16x8, gamma-scaled,   8 MB
//                    PRE-SWIZZLED: granule (s,h,g) holds c=s*64+g'*8..+8
//                    at slot g = g' ^ (h&7)  -> LDS linear copy yields
//                    the conflict-free ds_read_b128 tile directly.

__device__ __forceinline__ float gelu_fast(float x) {
    // gelu via A&S 7.1.26 erf approx (|erf err| < 1.5e-7); rcp/exp trans-pipe
    const float ax = fabsf(x);
    const float t  = __builtin_amdgcn_rcpf(1.0f + 0.3275911f * ax);
    const float p  = t * (0.254829592f +
                     t * (-0.284496736f +
                     t * (1.421413741f +
                     t * (-1.453152027f +
                     t * 1.061405429f))));
    const float e  = __expf(-x * x);
    const float er = copysignf(1.0f - p * e, x);
    return 0.5f * x * (1.0f + er);
}
__device__ __forceinline__ float sigmoid_(float x) {
    return 1.0f / (1.0f + __expf(-x));
}
__device__ __forceinline__ u16 f2bf(float x) {              // RNE f32->bf16
    u32 u = __float_as_uint(x);
    u32 r = (u + 0x7fffu + ((u >> 16) & 1u)) >> 16;
    return (u16)r;
}
__device__ __forceinline__ float bf2f(u16 u) {
    return __uint_as_float(((u32)u) << 16);
}

// ---------------------------------------------------------------------------
// K1 prep_misc, 577 blocks x 256 thr:
//  [0,256)   GBp[(l,cq)][j] = sum_{c in cq-slice} qt[l][c] W_film[c][j]
//  [256,512) fT[b][n][c] = bf16(feature[b][c][n])
//  [512,576) W1bf = bf16(W_mlp1)
//  576       counting sort of label_ids -> perm
// ---------------------------------------------------------------------------
__global__ __launch_bounds__(256) void prep_misc(
    const float* __restrict__ qt, const float* __restrict__ W_film,
    const float* __restrict__ feature, const float* __restrict__ W_mlp1,
    const int* __restrict__ label_ids,
    float* __restrict__ GBp, u16* __restrict__ W1bf, u16* __restrict__ fT,
    int* __restrict__ perm) {

    __shared__ __align__(16) char sm[16896];
    const int bid = blockIdx.x, t = threadIdx.x;

    if (bid < 256) {                       // ---- GB partials
        float* qrow = (float*)sm;
        const int l = bid >> 2, cq = bid & 3;
        if (t < 128) qrow[t] = qt[l * E_ + cq * 128 + t];
        __syncthreads();
        const float* wp = W_film + (size_t)(cq * 128) * 1024 + t * 4;
        f32x4 a = {0.f, 0.f, 0.f, 0.f};
        #pragma unroll 8
        for (int c = 0; c < 128; ++c) {
            const float4 w = *(const float4*)(wp + (size_t)c * 1024);
            const float q = qrow[c];
            a.x += q * w.x; a.y += q * w.y; a.z += q * w.z; a.w += q * w.w;
        }
        *(f32x4*)&GBp[(size_t)bid * 1024 + t * 4] = a;
    } else if (bid < 512) {                // ---- fT transpose
        float (*tile)[65] = (float(*)[65])sm;
        const int bb = bid - 256;
        const int b = bb >> 5, c0 = ((bb >> 2) & 7) * 64, n0 = (bb & 3) * 64;
        const float* fb = feature + (size_t)b * C_ * HW_;
        const int cl = t >> 2, nq = t & 3;
        #pragma unroll
        for (int i = 0; i < 4; ++i) {
            float4 v = *(const float4*)&fb[(c0 + cl) * HW_ + n0 + nq * 16 + i * 4];
            tile[cl][nq * 16 + i * 4 + 0] = v.x;
            tile[cl][nq * 16 + i * 4 + 1] = v.y;
            tile[cl][nq * 16 + i * 4 + 2] = v.z;
            tile[cl][nq * 16 + i * 4 + 3] = v.w;
        }
        __syncthreads();
        const int nl = t >> 2, cqq = t & 3;
        u16 pk[16];
        #pragma unroll
        for (int k = 0; k < 16; ++k) pk[k] = f2bf(tile[cqq * 16 + k][nl]);
        u16* dst = fT + (size_t)(b * HW_ + n0 + nl) * C_ + c0 + cqq * 16;
        *(uint4*)dst       = *(uint4*)pk;
        *(uint4*)(dst + 8) = *(uint4*)(pk + 8);
    } else if (bid < 576) {                // ---- W1 -> bf16
        const int b2 = bid - 512;
        #pragma unroll
        for (int k = 0; k < 2; ++k) {
            const int idx = (b2 * 512 + k * 256 + t) * 8;
            float4 v0 = *(const float4*)&W_mlp1[idx];
            float4 v1 = *(const float4*)&W_mlp1[idx + 4];
            u16 pk[8] = {f2bf(v0.x), f2bf(v0.y), f2bf(v0.z), f2bf(v0.w),
                         f2bf(v1.x), f2bf(v1.y), f2bf(v1.z), f2bf(v1.w)};
            *(uint4*)&W1bf[idx] = *(uint4*)pk;
        }
    } else {                               // ---- counting sort by label
        int* cnt = (int*)sm;
        if (t < 64) cnt[t] = 0;
        __syncthreads();
        const int l0 = label_ids[t], l1 = label_ids[t + 256];
        atomicAdd(&cnt[l0], 1);
        atomicAdd(&cnt[l1], 1);
        __syncthreads();
        if (t == 0) {
            int run = 0;
            for (int i = 0; i < 64; ++i) { const int c = cnt[i]; cnt[i] = run; run += c; }
        }
        __syncthreads();
        const int p0 = atomicAdd(&cnt[l0], 1);
        perm[p0] = t | (l0 << 16);
        const int p1 = atomicAdd(&cnt[l1], 1);
        perm[p1] = (t + 256) | (l1 << 16);
    }
}

// ---------------------------------------------------------------------------
// K2 prep_wg: 256 blocks (l, cq) x 256 thr.
//  Gl/Bl[l][c]; WgT in the pre-swizzled LDS-tile byte order (see ws layout);
//  Dlp[(l,cq)][h] = sum_{c slice} beta[c] W_att_h[c][h]  (fused, f32-exact)
// ---------------------------------------------------------------------------
__global__ __launch_bounds__(256) void prep_wg(
    const float* __restrict__ b_film, const float* __restrict__ W_att_h,
    const float* __restrict__ GBp,
    float* __restrict__ Gl, float* __restrict__ Bl,
    u16* __restrict__ WgT, float* __restrict__ Dlp) {

    __shared__ float g_s[128], b_s[128], dred[256];
    const int bid = blockIdx.x, t = threadIdx.x;
    const int l = bid >> 2, cq = bid & 3;

    if (t < 128) {
        const int c = cq * 128 + t;
        float g = b_film[c], be = b_film[512 + c];
        #pragma unroll
        for (int j = 0; j < 4; ++j) {
            g  += GBp[(size_t)(l * 4 + j) * 1024 + c];
            be += GBp[(size_t)(l * 4 + j) * 1024 + 512 + c];
        }
        g_s[t] = g; b_s[t] = be;
        Gl[l * C_ + c] = g;
        Bl[l * C_ + c] = be;
    }
    __syncthreads();

    const int h = t & 127, ch = t >> 7;
    const int s = cq * 2 + ch;                      // superstep in [0,8)
    char* dst = (char*)WgT + (size_t)l * 131072 + s * 16384 + h * 128;
    float dl = 0.f;
    #pragma unroll
    for (int g = 0; g < 8; ++g) {
        u16 pk[8];
        #pragma unroll
        for (int j = 0; j < 8; ++j) {
            const int cl = ch * 64 + g * 8 + j;     // local c in [0,128)
            const float w = W_att_h[(size_t)(cq * 128 + cl) * HATT_ + h];
            pk[j] = f2bf(g_s[cl] * w);
            dl += b_s[cl] * w;
        }
        *(uint4*)(dst + ((g ^ (h & 7)) * 16)) = *(uint4*)pk;
    }
    dred[t] = dl;
    __syncthreads();
    if (t < 128)
        Dlp[(size_t)(l * 4 + cq) * 128 + t] = dred[t] + dred[128 + t];
}

// ---------------------------------------------------------------------------
// K3 attn_gemm: 512 blocks x 512 thr (8 waves: 4 wm x 2 wc), one bq each,
// label-sorted + XCD-chunked (idx&7) -> per-XCD L2: fT 2MB + ~8 WgT = 3MB.
// K-loop: 8 supersteps BK=64, LDS dbuf 2x16KB, ONE barrier per superstep:
//   {issue 2 uint4 loads for s+1} {compute s: 2ks x (4 A-L2 + 4 swz ds_read
//    + 16 MFMA)} {2 ds_write_b128 -> other buf} {bar}
// Staging has ZERO gamma VALU (WgT pre-scaled + pre-swizzled).
// Epilogue: gelu -> attn -> pA + vectorized 4-way-split pooled p -> pP.
// ---------------------------------------------------------------------------
__global__ __launch_bounds__(512, 4) void attn_gemm(
    const float* __restrict__ W_att_f, const float* __restrict__ b_att_f,
    const float* __restrict__ b_att_h, const float* __restrict__ Dlp,
    const int*   __restrict__ perm,    const u16* __restrict__ WgT,
    const u16*   __restrict__ fT,
    float* __restrict__ pP, float* __restrict__ pA) {

    __shared__ __align__(16) char Bsh[32768];      // 2 x 16KB dbuf
    __shared__ float d_s[HATT_];
    __shared__ float wf_s[HATT_];
    __shared__ float attn_part[2][HW_];
    __shared__ float attn_s[HW_];

    const int t = threadIdx.x;
    const int srank = (blockIdx.x & 7) * 64 + (blockIdx.x >> 3);
    const int pe = perm[srank];
    const int bq = pe & 0xffff, l = pe >> 16;
    const int b = bq >> 6;

    if (t < HATT_) {
        d_s[t] = b_att_h[t]
               + Dlp[(size_t)(l * 4 + 0) * 128 + t]
               + Dlp[(size_t)(l * 4 + 1) * 128 + t]
               + Dlp[(size_t)(l * 4 + 2) * 128 + t]
               + Dlp[(size_t)(l * 4 + 3) * 128 + t];
        wf_s[t] = W_att_f[t];
    }

    const int lane = t & 63, w = t >> 6;
    const int wm = w >> 1, wc = w & 1;             // 4 n-quarters x 2 h-halves
    const int lr = lane & 15, lk = lane >> 4;
    const u16* Ab = fT + (size_t)b * HW_ * C_ + (size_t)(wm * 64 + lr) * C_ + lk * 8;
    const u16* Wl = WgT + (size_t)l * 65536;       // elements

    const f32x4 zero = {0.f, 0.f, 0.f, 0.f};
    f32x4 acc[4][4];
    #pragma unroll
    for (int mi = 0; mi < 4; ++mi)
        #pragma unroll
        for (int ni = 0; ni < 4; ++ni) acc[mi][ni] = zero;

    // prologue: stage superstep 0 into buf 0
    {
        const uint4 s0 = *(const uint4*)(Wl + (size_t)t * 8);
        const uint4 s1 = *(const uint4*)(Wl + (size_t)(512 + t) * 8);
        *(uint4*)(Bsh + t * 16)        = s0;
        *(uint4*)(Bsh + 8192 + t * 16) = s1;
    }
    __syncthreads();

    for (int s = 0; s < 8; ++s) {
        const int buf = s & 1;
        uint4 n0, n1;
        if (s < 7) {                               // issue next-tile loads NOW
            n0 = *(const uint4*)(Wl + (size_t)(s + 1) * 8192 + (size_t)t * 8);
            n1 = *(const uint4*)(Wl + (size_t)(s + 1) * 8192 + (size_t)(512 + t) * 8);
        }
        #pragma unroll
        for (int ks = 0; ks < 2; ++ks) {
            short8 af[4], bf[4];
            #pragma unroll
            for (int mi = 0; mi < 4; ++mi)
                af[mi] = *(const short8*)(Ab + (size_t)mi * 16 * C_ + s * 64 + ks * 32);
            #pragma unroll
            for (int ni = 0; ni < 4; ++ni) {
                const int h = wc * 64 + ni * 16 + lr;
                bf[ni] = *(const short8*)(Bsh + buf * 16384 + h * 128
                                          + (((ks * 4 + lk) ^ (h & 7)) * 16));
            }
            #pragma unroll
            for (int mi = 0; mi < 4; ++mi)
                #pragma unroll
                for (int ni = 0; ni < 4; ++ni)
                    acc[mi][ni] = __builtin_amdgcn_mfma_f32_16x16x32_bf16(
                        af[mi], bf[ni], acc[mi][ni], 0, 0, 0);
        }
        if (s < 7) {                               // write other buf (safe: 1 bar behind)
            *(uint4*)(Bsh + (buf ^ 1) * 16384 + t * 16)        = n0;
            *(uint4*)(Bsh + (buf ^ 1) * 16384 + 8192 + t * 16) = n1;
        }
        __syncthreads();
    }

    // ---- epilogue: gelu(hidden + D) . wf   (C/D: col(h)=lr, row(n)=lk*4+j)
    #pragma unroll
    for (int mi = 0; mi < 4; ++mi) {
        #pragma unroll
        for (int j = 0; j < 4; ++j) {
            float sum = 0.f;
            #pragma unroll
            for (int ni = 0; ni < 4; ++ni) {
                const int h = wc * 64 + ni * 16 + lr;
                sum += gelu_fast(acc[mi][ni][j] + d_s[h]) * wf_s[h];
            }
            sum += __shfl_xor(sum, 1);
            sum += __shfl_xor(sum, 2);
            sum += __shfl_xor(sum, 4);
            sum += __shfl_xor(sum, 8);
            if (lr == 0) attn_part[wc][wm * 64 + mi * 16 + lk * 4 + j] = sum;
        }
    }
    __syncthreads();
    if (t < HW_)
        attn_s[t] = sigmoid_(attn_part[0][t] + attn_part[1][t] + b_att_f[0]);
    __syncthreads();
    if (t < 64) {
        float a = attn_s[t] + attn_s[t + 64] + attn_s[t + 128] + attn_s[t + 192];
        #pragma unroll
        for (int m = 1; m < 64; m <<= 1) a += __shfl_xor(a, m);
        if (t == 0) pA[bq] = a;
    }

    // ---- p[c] = sum_n attn[n] fT[n][c]; 4-way n-split, 4 c's per thread
    float* pred = (float*)Bsh;                     // [4][512] f32, Bsh dead
    {
        const int ng = t >> 7, cb = (t & 127) * 4;
        const u16* fp = fT + (size_t)b * HW_ * C_ + cb;
        f32x4 p = zero;
        #pragma unroll 8
        for (int n = ng * 64; n < ng * 64 + 64; ++n) {
            const uint2 v = *(const uint2*)(fp + (size_t)n * C_);
            const float a = attn_s[n];
            p.x += a * __uint_as_float(v.x << 16);
            p.y += a * __uint_as_float(v.x & 0xffff0000u);
            p.z += a * __uint_as_float(v.y << 16);
            p.w += a * __uint_as_float(v.y & 0xffff0000u);
        }
        *(f32x4*)&pred[ng * 512 + cb] = p;
    }
    __syncthreads();
    pP[(size_t)bq * C_ + t] = pred[t] + pred[512 + t] + pred[1024 + t] + pred[1536 + t];
}

// ---------------------------------------------------------------------------
// K4 mlp_head: 256 blocks x 512 thr, 2 bq per block.
// ---------------------------------------------------------------------------
__global__ __launch_bounds__(512) void mlp_head(
    const int*   __restrict__ label_ids,
    const float* __restrict__ Gl, const float* __restrict__ Bl,
    const float* __restrict__ b_mlp1, const float* __restrict__ W_mlp2,
    const float* __restrict__ b_mlp2, const float* __restrict__ pP,
    const float* __restrict__ pA,     const u16* __restrict__ W1bf,
    float* __restrict__ out) {

    __shared__ float pooled_s[2][C_];
    __shared__ float zred[2][2][HMLP_];
    __shared__ float z_s[2][HMLP_];
    __shared__ float red_s[32 * NCLS_];

    const int t = threadIdx.x;
    const int bq0 = blockIdx.x * 2;

    {
        const int bqi = t >> 8, cc = (t & 255) * 2;
        const int bq = bq0 + bqi, l = label_ids[bq];
        const float A = pA[bq];
        const float inv = 1.0f / (A + 1e-8f);
        #pragma unroll
        for (int i = 0; i < 2; ++i) {
            const int c = cc + i;
            const float p = pP[(size_t)bq * C_ + c];
            pooled_s[bqi][c] = (Gl[l * C_ + c] * p + Bl[l * C_ + c] * A) * inv;
        }
    }
    __syncthreads();

    {
        const int hp = t & 255, cg = t >> 8;
        float z00 = 0.f, z01 = 0.f, z10 = 0.f, z11 = 0.f;
        const u16* wp = W1bf + hp * 2;
        #pragma unroll 8
        for (int c = cg * 256; c < cg * 256 + 256; ++c) {
            const u32 v = *(const u32*)(wp + (size_t)c * HMLP_);
            const float w0 = __uint_as_float(v << 16);
            const float w1 = __uint_as_float(v & 0xffff0000u);
            const float pa = pooled_s[0][c], pb = pooled_s[1][c];
            z00 += pa * w0; z01 += pa * w1;
            z10 += pb * w0; z11 += pb * w1;
        }
        float2 a0 = {z00, z01}, a1 = {z10, z11};
        *(float2*)&zred[cg][0][hp * 2] = a0;
        *(float2*)&zred[cg][1][hp * 2] = a1;
    }
    __syncthreads();
    {
        const int bqi = t >> 8, h2 = (t & 255) * 2;
        #pragma unroll
        for (int i = 0; i < 2; ++i) {
            const int h = h2 + i;
            z_s[bqi][h] = gelu_fast(zred[0][bqi][h] + zred[1][bqi][h] + b_mlp1[h]);
        }
    }
    __syncthreads();

    #pragma unroll
    for (int bqi = 0; bqi < 2; ++bqi) {
        if (t < 448) {
            const int o = t % 14, seg = t / 14;
            float s = 0.f;
            #pragma unroll
            for (int k = 0; k < 16; ++k) {
                const int h = seg * 16 + k;
                s += z_s[bqi][h] * W_mlp2[h * NCLS_ + o];
            }
            red_s[seg * NCLS_ + o] = s;
        }
        __syncthreads();
        if (t < NCLS_) {
            float s = b_mlp2[t];
            #pragma unroll
            for (int seg = 0; seg < 32; ++seg) s += red_s[seg * NCLS_ + t];
            out[(bq0 + bqi) * NCLS_ + t] = s;
        }
        __syncthreads();
    }
}

// ---------------------------------------------------------------------------
extern "C" void kernel_launch(void* const* d_in, const int* in_sizes, int n_in,
                              void* d_out, int out_size, void* d_ws, size_t ws_size,
                              hipStream_t stream) {
    const float* feature   = (const float*)d_in[0];
    const int*   label_ids = (const int*)  d_in[1];
    const float* qt        = (const float*)d_in[2];
    const float* W_film    = (const float*)d_in[3];
    const float* b_film    = (const float*)d_in[4];
    const float* W_att_h   = (const float*)d_in[5];
    const float* b_att_h   = (const float*)d_in[6];
    const float* W_att_f   = (const float*)d_in[7];
    const float* b_att_f   = (const float*)d_in[8];
    const float* W_mlp1    = (const float*)d_in[9];
    const float* b_mlp1    = (const float*)d_in[10];
    const float* W_mlp2    = (const float*)d_in[11];
    const float* b_mlp2    = (const float*)d_in[12];
    float* out = (float*)d_out;

    char* wsb   = (char*)d_ws;
    float* GBp  = (float*)wsb;                   // 1 MB (k1 -> k2)
    float* pP   = (float*)wsb;                   // 1 MB (k3 -> k4, aliases GBp)
    float* pA   = (float*)(wsb + 1048576);       // 2 KB
    int*   perm = (int*)  (wsb + 1050624);       // 2 KB
    float* Dlp  = (float*)(wsb + 1052672);       // 128 KB
    float* Gl   = (float*)(wsb + 1183744);       // 128 KB
    float* Bl   = (float*)(wsb + 1314816);       // 128 KB
    u16*   W1bf = (u16*)  (wsb + 1445888);       // 512 KB
    u16*   fTp  = (u16*)  (wsb + 1970176);       // 2 MB
    u16*   WgT  = (u16*)  (wsb + 4067328);       // 8 MB

    hipLaunchKernelGGL(prep_misc, dim3(577), dim3(256), 0, stream,
                       qt, W_film, feature, W_mlp1, label_ids,
                       GBp, W1bf, fTp, perm);
    hipLaunchKernelGGL(prep_wg, dim3(256), dim3(256), 0, stream,
                       b_film, W_att_h, GBp, Gl, Bl, WgT, Dlp);
    hipLaunchKernelGGL(attn_gemm, dim3(512), dim3(512), 0, stream,
                       W_att_f, b_att_f, b_att_h, Dlp, perm, WgT, fTp, pP, pA);
    hipLaunchKernelGGL(mlp_head, dim3(256), dim3(512), 0, stream,
                       label_ids, Gl, Bl, b_mlp1, W_mlp2, b_mlp2,
                       pP, pA, W1bf, out);
}

// Round 8
// 67.943 us; speedup vs baseline: 1.6508x; 1.2777x over previous
//
#include <hip/hip_runtime.h>
#include <hip/hip_bf16.h>

#define B_    8
#define Q_    64
#define C_    512
#define HW_   256
#define E_    512
#define HATT_ 128
#define HMLP_ 512
#define NCLS_ 14
#define NLAB_ 64

typedef unsigned short u16;
typedef unsigned int   u32;
typedef __attribute__((ext_vector_type(8))) short short8;   // 8 bf16
typedef __attribute__((ext_vector_type(4))) float f32x4;

// ws layout (bytes) — total ~12.29 MB < 12.58 MB proven available (R2):
//   GBp  @ 0       : 256x1024 f32 (l,cq)-partials of [gamma|beta]   1 MB
//                    (aliased by pP 512x512 f32 after prep_wg consumed it)
//   pA   @ 1048576 : 512 f32 attn mass per bq                        2 KB
//   perm @ 1050624 : 512 int label-sorted bq list (bq | l<<16)       2 KB
//   Dlp  @ 1052672 : 256x128 f32 (l,cq)-partials of beta@W_att_h   128 KB
//   Gl   @ 1183744 : 64x512 f32 gamma per label                    128 KB
//   Bl   @ 1314816 : 64x512 f32 beta per label                     128 KB
//   W1bf @ 1445888 : 512x512 bf16 W_mlp1                           512 KB
//   fT   @ 1970176 : 8x256x512 bf16 feature^T [b][n][c]              2 MB
//   WgT  @ 4067328 : 64 x [8ss][128h][8slot] bf16x8 gamma-scaled,    8 MB
//                    pre-swizzled (slot = g' ^ (h&7)) -> linear DMA
//                    into LDS yields the conflict-free tile directly.

__device__ __forceinline__ float gelu_fast(float x) {
    // gelu via A&S 7.1.26 erf approx (|erf err| < 1.5e-7); rcp/exp trans-pipe
    const float ax = fabsf(x);
    const float t  = __builtin_amdgcn_rcpf(1.0f + 0.3275911f * ax);
    const float p  = t * (0.254829592f +
                     t * (-0.284496736f +
                     t * (1.421413741f +
                     t * (-1.453152027f +
                     t * 1.061405429f))));
    const float e  = __expf(-x * x);
    const float er = copysignf(1.0f - p * e, x);
    return 0.5f * x * (1.0f + er);
}
__device__ __forceinline__ float sigmoid_(float x) {
    return 1.0f / (1.0f + __expf(-x));
}
__device__ __forceinline__ u16 f2bf(float x) {              // RNE f32->bf16
    u32 u = __float_as_uint(x);
    u32 r = (u + 0x7fffu + ((u >> 16) & 1u)) >> 16;
    return (u16)r;
}
__device__ __forceinline__ float bf2f(u16 u) {
    return __uint_as_float(((u32)u) << 16);
}
// async global->LDS DMA, 16B per lane; LDS dest = wave-uniform base + lane*16
__device__ __forceinline__ void gl2lds16(const void* gsrc, void* ldsdst) {
    __builtin_amdgcn_global_load_lds(
        (const __attribute__((address_space(1))) u32*)gsrc,
        (__attribute__((address_space(3))) u32*)ldsdst, 16, 0, 0);
}

// ---------------------------------------------------------------------------
// K1 prep_misc, 577 blocks x 256 thr:
//  [0,256)   GBp[(l,cq)][j] = sum_{c in cq-slice} qt[l][c] W_film[c][j]
//  [256,512) fT[b][n][c] = bf16(feature[b][c][n])
//  [512,576) W1bf = bf16(W_mlp1)
//  576       counting sort of label_ids -> perm
// ---------------------------------------------------------------------------
__global__ __launch_bounds__(256) void prep_misc(
    const float* __restrict__ qt, const float* __restrict__ W_film,
    const float* __restrict__ feature, const float* __restrict__ W_mlp1,
    const int* __restrict__ label_ids,
    float* __restrict__ GBp, u16* __restrict__ W1bf, u16* __restrict__ fT,
    int* __restrict__ perm) {

    __shared__ __align__(16) char sm[16896];
    const int bid = blockIdx.x, t = threadIdx.x;

    if (bid < 256) {                       // ---- GB partials
        float* qrow = (float*)sm;
        const int l = bid >> 2, cq = bid & 3;
        if (t < 128) qrow[t] = qt[l * E_ + cq * 128 + t];
        __syncthreads();
        const float* wp = W_film + (size_t)(cq * 128) * 1024 + t * 4;
        f32x4 a = {0.f, 0.f, 0.f, 0.f};
        #pragma unroll 8
        for (int c = 0; c < 128; ++c) {
            const float4 w = *(const float4*)(wp + (size_t)c * 1024);
            const float q = qrow[c];
            a.x += q * w.x; a.y += q * w.y; a.z += q * w.z; a.w += q * w.w;
        }
        *(f32x4*)&GBp[(size_t)bid * 1024 + t * 4] = a;
    } else if (bid < 512) {                // ---- fT transpose
        float (*tile)[65] = (float(*)[65])sm;
        const int bb = bid - 256;
        const int b = bb >> 5, c0 = ((bb >> 2) & 7) * 64, n0 = (bb & 3) * 64;
        const float* fb = feature + (size_t)b * C_ * HW_;
        const int cl = t >> 2, nq = t & 3;
        #pragma unroll
        for (int i = 0; i < 4; ++i) {
            float4 v = *(const float4*)&fb[(c0 + cl) * HW_ + n0 + nq * 16 + i * 4];
            tile[cl][nq * 16 + i * 4 + 0] = v.x;
            tile[cl][nq * 16 + i * 4 + 1] = v.y;
            tile[cl][nq * 16 + i * 4 + 2] = v.z;
            tile[cl][nq * 16 + i * 4 + 3] = v.w;
        }
        __syncthreads();
        const int nl = t >> 2, cqq = t & 3;
        u16 pk[16];
        #pragma unroll
        for (int k = 0; k < 16; ++k) pk[k] = f2bf(tile[cqq * 16 + k][nl]);
        u16* dst = fT + (size_t)(b * HW_ + n0 + nl) * C_ + c0 + cqq * 16;
        *(uint4*)dst       = *(uint4*)pk;
        *(uint4*)(dst + 8) = *(uint4*)(pk + 8);
    } else if (bid < 576) {                // ---- W1 -> bf16
        const int b2 = bid - 512;
        #pragma unroll
        for (int k = 0; k < 2; ++k) {
            const int idx = (b2 * 512 + k * 256 + t) * 8;
            float4 v0 = *(const float4*)&W_mlp1[idx];
            float4 v1 = *(const float4*)&W_mlp1[idx + 4];
            u16 pk[8] = {f2bf(v0.x), f2bf(v0.y), f2bf(v0.z), f2bf(v0.w),
                         f2bf(v1.x), f2bf(v1.y), f2bf(v1.z), f2bf(v1.w)};
            *(uint4*)&W1bf[idx] = *(uint4*)pk;
        }
    } else {                               // ---- counting sort by label
        int* cnt = (int*)sm;
        if (t < 64) cnt[t] = 0;
        __syncthreads();
        const int l0 = label_ids[t], l1 = label_ids[t + 256];
        atomicAdd(&cnt[l0], 1);
        atomicAdd(&cnt[l1], 1);
        __syncthreads();
        if (t == 0) {
            int run = 0;
            for (int i = 0; i < 64; ++i) { const int c = cnt[i]; cnt[i] = run; run += c; }
        }
        __syncthreads();
        const int p0 = atomicAdd(&cnt[l0], 1);
        perm[p0] = t | (l0 << 16);
        const int p1 = atomicAdd(&cnt[l1], 1);
        perm[p1] = (t + 256) | (l1 << 16);
    }
}

// ---------------------------------------------------------------------------
// K2 prep_wg: 256 blocks (l, cq) x 256 thr.
//  Gl/Bl[l][c]; WgT in the pre-swizzled LDS-tile byte order (see ws layout);
//  Dlp[(l,cq)][h] = sum_{c slice} beta[c] W_att_h[c][h]  (fused, f32-exact)
// ---------------------------------------------------------------------------
__global__ __launch_bounds__(256) void prep_wg(
    const float* __restrict__ b_film, const float* __restrict__ W_att_h,
    const float* __restrict__ GBp,
    float* __restrict__ Gl, float* __restrict__ Bl,
    u16* __restrict__ WgT, float* __restrict__ Dlp) {

    __shared__ float g_s[128], b_s[128], dred[256];
    const int bid = blockIdx.x, t = threadIdx.x;
    const int l = bid >> 2, cq = bid & 3;

    if (t < 128) {
        const int c = cq * 128 + t;
        float g = b_film[c], be = b_film[512 + c];
        #pragma unroll
        for (int j = 0; j < 4; ++j) {
            g  += GBp[(size_t)(l * 4 + j) * 1024 + c];
            be += GBp[(size_t)(l * 4 + j) * 1024 + 512 + c];
        }
        g_s[t] = g; b_s[t] = be;
        Gl[l * C_ + c] = g;
        Bl[l * C_ + c] = be;
    }
    __syncthreads();

    const int h = t & 127, ch = t >> 7;
    const int s = cq * 2 + ch;                      // superstep in [0,8)
    char* dst = (char*)WgT + (size_t)l * 131072 + s * 16384 + h * 128;
    float dl = 0.f;
    #pragma unroll
    for (int g = 0; g < 8; ++g) {
        u16 pk[8];
        #pragma unroll
        for (int j = 0; j < 8; ++j) {
            const int cl = ch * 64 + g * 8 + j;     // local c in [0,128)
            const float w = W_att_h[(size_t)(cq * 128 + cl) * HATT_ + h];
            pk[j] = f2bf(g_s[cl] * w);
            dl += b_s[cl] * w;
        }
        *(uint4*)(dst + ((g ^ (h & 7)) * 16)) = *(uint4*)pk;
    }
    dred[t] = dl;
    __syncthreads();
    if (t < 128)
        Dlp[(size_t)(l * 4 + cq) * 128 + t] = dred[t] + dred[128 + t];
}

// ---------------------------------------------------------------------------
// K3 attn_gemm: 512 blocks x 512 thr (8 waves: 4 wm x 2 wc), one bq each,
// label-sorted + XCD-chunked. m97-structure K-loop: BOTH operands staged via
// async global_load_lds width-16 (A: fT with inverse-swizzled source; B: WgT
// already in linear-DMA byte order), single-buffer, 2 barriers/superstep.
// Inner loop is pure swizzled ds_read_b128 + MFMA. 8 ss of BK=64, K=512.
// Epilogue: gelu -> attn -> pA + 4-way-split pooled p -> pP.
// ---------------------------------------------------------------------------
__global__ __launch_bounds__(512, 4) void attn_gemm(
    const float* __restrict__ W_att_f, const float* __restrict__ b_att_f,
    const float* __restrict__ b_att_h, const float* __restrict__ Dlp,
    const int*   __restrict__ perm,    const u16* __restrict__ WgT,
    const u16*   __restrict__ fT,
    float* __restrict__ pP, float* __restrict__ pA) {

    __shared__ __align__(16) char Ash[32768];      // 256n x 64c bf16, swizzled
    __shared__ __align__(16) char Bsh[16384];      // 128h x 64c bf16, swizzled
    __shared__ float d_s[HATT_];
    __shared__ float wf_s[HATT_];
    __shared__ float attn_part[2][HW_];
    __shared__ float attn_s[HW_];

    const int t = threadIdx.x;
    const int srank = (blockIdx.x & 7) * 64 + (blockIdx.x >> 3);
    const int pe = perm[srank];
    const int bq = pe & 0xffff, l = pe >> 16;
    const int b = bq >> 6;

    if (t < HATT_) {
        d_s[t] = b_att_h[t]
               + Dlp[(size_t)(l * 4 + 0) * 128 + t]
               + Dlp[(size_t)(l * 4 + 1) * 128 + t]
               + Dlp[(size_t)(l * 4 + 2) * 128 + t]
               + Dlp[(size_t)(l * 4 + 3) * 128 + t];
        wf_s[t] = W_att_f[t];
    }

    const u16* fTb = fT + (size_t)b * HW_ * C_;
    const u16* Wl  = WgT + (size_t)l * 65536;      // elements

    // staging geometry: A granule g = it*512+t -> LDS byte g*16, row n=g>>3,
    // src slot = (g&7) ^ (n&7)  (inverse swizzle on SOURCE, LDS dest linear)
    const int an  = t >> 3;                        // n = it*64 + an
    const int asl = (t & 7) ^ (an & 7);            // it*64 preserves n&7

    #define STAGE(s_) {                                                       \
        _Pragma("unroll")                                                     \
        for (int it = 0; it < 4; ++it)                                        \
            gl2lds16(fTb + (size_t)(it * 64 + an) * C_ + (s_) * 64 + asl * 8, \
                     Ash + (it * 512 + t) * 16);                              \
        _Pragma("unroll")                                                     \
        for (int it = 0; it < 2; ++it)                                        \
            gl2lds16(Wl + (size_t)(s_) * 8192 + (size_t)(it * 512 + t) * 8,   \
                     Bsh + (it * 512 + t) * 16);                              \
    }

    const int lane = t & 63, w = t >> 6;
    const int wm = w >> 1, wc = w & 1;             // 4 n-quarters x 2 h-halves
    const int lr = lane & 15, lk = lane >> 4;

    const f32x4 zero = {0.f, 0.f, 0.f, 0.f};
    f32x4 acc[4][4];
    #pragma unroll
    for (int mi = 0; mi < 4; ++mi)
        #pragma unroll
        for (int ni = 0; ni < 4; ++ni) acc[mi][ni] = zero;

    STAGE(0);
    __syncthreads();                               // drains DMA (vmcnt 0)

    for (int s = 0; s < 8; ++s) {
        #pragma unroll
        for (int ks = 0; ks < 2; ++ks) {
            const int slot = ks * 4 + lk;
            short8 af[4], bf[4];
            #pragma unroll
            for (int mi = 0; mi < 4; ++mi) {
                const int nl = wm * 64 + mi * 16 + lr;
                af[mi] = *(const short8*)(Ash + nl * 128 + ((slot ^ (nl & 7)) * 16));
            }
            #pragma unroll
            for (int ni = 0; ni < 4; ++ni) {
                const int h = wc * 64 + ni * 16 + lr;
                bf[ni] = *(const short8*)(Bsh + h * 128 + ((slot ^ (h & 7)) * 16));
            }
            #pragma unroll
            for (int mi = 0; mi < 4; ++mi)
                #pragma unroll
                for (int ni = 0; ni < 4; ++ni)
                    acc[mi][ni] = __builtin_amdgcn_mfma_f32_16x16x32_bf16(
                        af[mi], bf[ni], acc[mi][ni], 0, 0, 0);
        }
        if (s < 7) {
            __syncthreads();                       // all reads of buf done
            STAGE(s + 1);                          // async refill
        }
        __syncthreads();                           // DMA drained / epilogue gate
    }

    // ---- epilogue: gelu(hidden + D) . wf   (C/D: col(h)=lr, row(n)=lk*4+j)
    #pragma unroll
    for (int mi = 0; mi < 4; ++mi) {
        #pragma unroll
        for (int j = 0; j < 4; ++j) {
            float sum = 0.f;
            #pragma unroll
            for (int ni = 0; ni < 4; ++ni) {
                const int h = wc * 64 + ni * 16 + lr;
                sum += gelu_fast(acc[mi][ni][j] + d_s[h]) * wf_s[h];
            }
            sum += __shfl_xor(sum, 1);
            sum += __shfl_xor(sum, 2);
            sum += __shfl_xor(sum, 4);
            sum += __shfl_xor(sum, 8);
            if (lr == 0) attn_part[wc][wm * 64 + mi * 16 + lk * 4 + j] = sum;
        }
    }
    __syncthreads();
    if (t < HW_)
        attn_s[t] = sigmoid_(attn_part[0][t] + attn_part[1][t] + b_att_f[0]);
    __syncthreads();
    if (t < 64) {
        float a = attn_s[t] + attn_s[t + 64] + attn_s[t + 128] + attn_s[t + 192];
        #pragma unroll
        for (int m = 1; m < 64; m <<= 1) a += __shfl_xor(a, m);
        if (t == 0) pA[bq] = a;
    }

    // ---- p[c] = sum_n attn[n] fT[n][c]; 4-way n-split, 4 c's per thread
    float* pred = (float*)Ash;                     // [4][512] f32, Ash dead
    {
        const int ng = t >> 7, cb = (t & 127) * 4;
        const u16* fp = fTb + cb;
        f32x4 p = zero;
        #pragma unroll 8
        for (int n = ng * 64; n < ng * 64 + 64; ++n) {
            const uint2 v = *(const uint2*)(fp + (size_t)n * C_);
            const float a = attn_s[n];
            p.x += a * __uint_as_float(v.x << 16);
            p.y += a * __uint_as_float(v.x & 0xffff0000u);
            p.z += a * __uint_as_float(v.y << 16);
            p.w += a * __uint_as_float(v.y & 0xffff0000u);
        }
        *(f32x4*)&pred[ng * 512 + cb] = p;
    }
    __syncthreads();
    pP[(size_t)bq * C_ + t] = pred[t] + pred[512 + t] + pred[1024 + t] + pred[1536 + t];
}

// ---------------------------------------------------------------------------
// K4 mlp_head: 256 blocks x 512 thr, 2 bq per block.
// ---------------------------------------------------------------------------
__global__ __launch_bounds__(512) void mlp_head(
    const int*   __restrict__ label_ids,
    const float* __restrict__ Gl, const float* __restrict__ Bl,
    const float* __restrict__ b_mlp1, const float* __restrict__ W_mlp2,
    const float* __restrict__ b_mlp2, const float* __restrict__ pP,
    const float* __restrict__ pA,     const u16* __restrict__ W1bf,
    float* __restrict__ out) {

    __shared__ float pooled_s[2][C_];
    __shared__ float zred[2][2][HMLP_];
    __shared__ float z_s[2][HMLP_];
    __shared__ float red_s[32 * NCLS_];

    const int t = threadIdx.x;
    const int bq0 = blockIdx.x * 2;

    {
        const int bqi = t >> 8, cc = (t & 255) * 2;
        const int bq = bq0 + bqi, l = label_ids[bq];
        const float A = pA[bq];
        const float inv = 1.0f / (A + 1e-8f);
        #pragma unroll
        for (int i = 0; i < 2; ++i) {
            const int c = cc + i;
            const float p = pP[(size_t)bq * C_ + c];
            pooled_s[bqi][c] = (Gl[l * C_ + c] * p + Bl[l * C_ + c] * A) * inv;
        }
    }
    __syncthreads();

    {
        const int hp = t & 255, cg = t >> 8;
        float z00 = 0.f, z01 = 0.f, z10 = 0.f, z11 = 0.f;
        const u16* wp = W1bf + hp * 2;
        #pragma unroll 8
        for (int c = cg * 256; c < cg * 256 + 256; ++c) {
            const u32 v = *(const u32*)(wp + (size_t)c * HMLP_);
            const float w0 = __uint_as_float(v << 16);
            const float w1 = __uint_as_float(v & 0xffff0000u);
            const float pa = pooled_s[0][c], pb = pooled_s[1][c];
            z00 += pa * w0; z01 += pa * w1;
            z10 += pb * w0; z11 += pb * w1;
        }
        float2 a0 = {z00, z01}, a1 = {z10, z11};
        *(float2*)&zred[cg][0][hp * 2] = a0;
        *(float2*)&zred[cg][1][hp * 2] = a1;
    }
    __syncthreads();
    {
        const int bqi = t >> 8, h2 = (t & 255) * 2;
        #pragma unroll
        for (int i = 0; i < 2; ++i) {
            const int h = h2 + i;
            z_s[bqi][h] = gelu_fast(zred[0][bqi][h] + zred[1][bqi][h] + b_mlp1[h]);
        }
    }
    __syncthreads();

    #pragma unroll
    for (int bqi = 0; bqi < 2; ++bqi) {
        if (t < 448) {
            const int o = t % 14, seg = t / 14;
            float s = 0.f;
            #pragma unroll
            for (int k = 0; k < 16; ++k) {
                const int h = seg * 16 + k;
                s += z_s[bqi][h] * W_mlp2[h * NCLS_ + o];
            }
            red_s[seg * NCLS_ + o] = s;
        }
        __syncthreads();
        if (t < NCLS_) {
            float s = b_mlp2[t];
            #pragma unroll
            for (int seg = 0; seg < 32; ++seg) s += red_s[seg * NCLS_ + t];
            out[(bq0 + bqi) * NCLS_ + t] = s;
        }
        __syncthreads();
    }
}

// ---------------------------------------------------------------------------
extern "C" void kernel_launch(void* const* d_in, const int* in_sizes, int n_in,
                              void* d_out, int out_size, void* d_ws, size_t ws_size,
                              hipStream_t stream) {
    const float* feature   = (const float*)d_in[0];
    const int*   label_ids = (const int*)  d_in[1];
    const float* qt        = (const float*)d_in[2];
    const float* W_film    = (const float*)d_in[3];
    const float* b_film    = (const float*)d_in[4];
    const float* W_att_h   = (const float*)d_in[5];
    const float* b_att_h   = (const float*)d_in[6];
    const float* W_att_f   = (const float*)d_in[7];
    const float* b_att_f   = (const float*)d_in[8];
    const float* W_mlp1    = (const float*)d_in[9];
    const float* b_mlp1    = (const float*)d_in[10];
    const float* W_mlp2    = (const float*)d_in[11];
    const float* b_mlp2    = (const float*)d_in[12];
    float* out = (float*)d_out;

    char* wsb   = (char*)d_ws;
    float* GBp  = (float*)wsb;                   // 1 MB (k1 -> k2)
    float* pP   = (float*)wsb;                   // 1 MB (k3 -> k4, aliases GBp)
    float* pA   = (float*)(wsb + 1048576);       // 2 KB
    int*   perm = (int*)  (wsb + 1050624);       // 2 KB
    float* Dlp  = (float*)(wsb + 1052672);       // 128 KB
    float* Gl   = (float*)(wsb + 1183744);       // 128 KB
    float* Bl   = (float*)(wsb + 1314816);       // 128 KB
    u16*   W1bf = (u16*)  (wsb + 1445888);       // 512 KB
    u16*   fTp  = (u16*)  (wsb + 1970176);       // 2 MB
    u16*   WgT  = (u16*)  (wsb + 4067328);       // 8 MB

    hipLaunchKernelGGL(prep_misc, dim3(577), dim3(256), 0, stream,
                       qt, W_film, feature, W_mlp1, label_ids,
                       GBp, W1bf, fTp, perm);
    hipLaunchKernelGGL(prep_wg, dim3(256), dim3(256), 0, stream,
                       b_film, W_att_h, GBp, Gl, Bl, WgT, Dlp);
    hipLaunchKernelGGL(attn_gemm, dim3(512), dim3(512), 0, stream,
                       W_att_f, b_att_f, b_att_h, Dlp, perm, WgT, fTp, pP, pA);
    hipLaunchKernelGGL(mlp_head, dim3(256), dim3(512), 0, stream,
                       label_ids, Gl, Bl, b_mlp1, W_mlp2, b_mlp2,
                       pP, pA, W1bf, out);
}